// Round 3
// baseline (633.343 us; speedup 1.0000x reference)
//
#include <hip/hip_runtime.h>

// f32 I/O. K=8 expert AEs, B=8192, D=1024, H=256.
//   h = relu(x @ W1[k] + b1[k]); recon = h @ W2[k] + b2[k]
//   err[k,b] = mean((recon-x)^2); out[b] = recon[argmin_k err, b]
// Precision (validated R2): pass1 err via split-bf16 hi/lo 3-product GEMMs;
// pass2 winner recon plain bf16-hi.
// R6: 2-stage reg double-buffer + reg-held h in phase B -> 428us total,
// pass1 230us, MfmaUtil 40%. Phase A loads x frags 4x-duplicated (all 4
// waves read all 4 m-tiles); phase B re-reads W2 twice.
// R7 (global_load_lds staging) failed opaquely -> suspect the AS-cast builtin.
// R8 (this rev): same traffic cuts, standard constructs only:
//  - phase A: x dedup 4x->1x via reg-staged LDS ring (T14 issue-early/
//    write-late: wave wv global_loads its own mt=wv frags for the NEXT
//    4-it group right after the barrier, ds_writes them after this group's
//    MFMAs, 1 barrier per 4 its). W1 stays in 2-stage reg double-buffer.
//  - phase B: single dt loop, W2 frags read ONCE: mt 0-1 h in regs
//    (128 VGPR), mt 2-3 h from swizzled LDS (<=2-way conflicts).
//  - pass2: x staged in 4-it chunks (barriers 64 -> 16).

#define KE 8
#define NB 8192
#define ND 1024
#define NH 256

typedef float f32x4 __attribute__((ext_vector_type(4)));
typedef short s16x8 __attribute__((ext_vector_type(8)));
typedef unsigned short u16x8 __attribute__((ext_vector_type(8)));

__device__ __forceinline__ float bf2f(unsigned short h) {
  union { unsigned int u; float f; } v; v.u = ((unsigned int)h) << 16; return v.f;
}
__device__ __forceinline__ unsigned short f2bf(float f) {
  union { unsigned int u; float f; } v; v.f = f;
  unsigned int u = v.u;
  u += 0x7fffu + ((u >> 16) & 1u);   // RTNE
  return (unsigned short)(u >> 16);
}
__device__ __forceinline__ void split2(float x, unsigned short& hi, unsigned short& lo) {
  hi = f2bf(x);
  lo = f2bf(x - bf2f(hi));
}

// ---- fused pack: W1, W2, x -> frag-ordered hi/lo arrays; also zeroes cnt.
__global__ __launch_bounds__(256) void pack_all(
    const float* __restrict__ W1, unsigned short* __restrict__ w1oh, unsigned short* __restrict__ w1ol,
    const float* __restrict__ W2, unsigned short* __restrict__ w2oh, unsigned short* __restrict__ w2ol,
    const float* __restrict__ xin, unsigned short* __restrict__ xoh, unsigned short* __restrict__ xol,
    unsigned int* __restrict__ cnt) {
  const int bx = blockIdx.x;
  const int tid = threadIdx.x;
  if (bx == 0 && tid < KE) cnt[tid] = 0;

  if (bx < 1024) {                           // ---- pack W1
    int gid = bx * 256 + tid;
    int L = gid & 63;
    int g = gid >> 6;
    int ks = g & 31;
    int ct = (g >> 5) & 15;
    int k = g >> 9;
    int col = ct * 16 + (L & 15);
    int kd0 = ks * 32 + (L >> 4) * 8;
    unsigned short th[8], tl[8];
#pragma unroll
    for (int j = 0; j < 8; ++j) {
      float v = W1[((size_t)k * ND + kd0 + j) * NH + col];
      split2(v, th[j], tl[j]);
    }
    size_t o = ((size_t)g * 64 + L) * 8;
    *(u16x8*)&w1oh[o] = *(u16x8*)th;
    *(u16x8*)&w1ol[o] = *(u16x8*)tl;
  } else if (bx < 2048) {                    // ---- pack W2
    int gid = (bx - 1024) * 256 + tid;
    int L = gid & 63;
    int g = gid >> 6;
    int ks = g & 7;
    int dt = (g >> 3) & 63;
    int k = g >> 9;
    int d2 = dt * 16 + (L & 15);
    int h0 = ks * 32 + (L >> 4) * 8;
    unsigned short th[8], tl[8];
#pragma unroll
    for (int j = 0; j < 8; ++j) {
      float v = W2[((size_t)k * NH + h0 + j) * ND + d2];
      split2(v, th[j], tl[j]);
    }
    size_t o = ((size_t)g * 64 + L) * 8;
    *(u16x8*)&w2oh[o] = *(u16x8*)th;
    *(u16x8*)&w2ol[o] = *(u16x8*)tl;
  } else {                                   // ---- pack x
    int gid = (bx - 2048) * 256 + tid;
    int L = gid & 63;
    int g = gid >> 6;
    int ks = g & 31;
    int rt = g >> 5;
    int row = rt * 16 + (L & 15);
    int kd0 = ks * 32 + (L >> 4) * 8;
    float4 a = *(const float4*)&xin[(size_t)row * ND + kd0];
    float4 b = *(const float4*)&xin[(size_t)row * ND + kd0 + 4];
    unsigned short th[8], tl[8];
    split2(a.x, th[0], tl[0]); split2(a.y, th[1], tl[1]);
    split2(a.z, th[2], tl[2]); split2(a.w, th[3], tl[3]);
    split2(b.x, th[4], tl[4]); split2(b.y, th[5], tl[5]);
    split2(b.z, th[6], tl[6]); split2(b.w, th[7], tl[7]);
    size_t o = ((size_t)g * 64 + L) * 8;
    *(u16x8*)&xoh[o] = *(u16x8*)th;
    *(u16x8*)&xol[o] = *(u16x8*)tl;
  }
}

// load one W1 stage (8 frags, 128B/lane) into named register buffers
#define LOADW1(bh, bl, it)                              \
  do {                                                  \
    _Pragma("unroll")                                   \
    for (int nt_ = 0; nt_ < 4; ++nt_) {                 \
      int o_ = wo1[nt_] + (it) * 512;                   \
      bh[nt_] = *(const s16x8*)&w1ph[o_];               \
      bl[nt_] = *(const s16x8*)&w1pl[o_];               \
    }                                                   \
  } while (0)

// issue global loads for 4 its of this wave's x frags (mt=wv, hi+lo) -> regs
#define GLOADX(itb)                                     \
  do {                                                  \
    _Pragma("unroll")                                   \
    for (int q_ = 0; q_ < 4; ++q_) {                    \
      size_t go_ = xgbase + (size_t)((itb) + q_) * 512; \
      xg[q_][0] = *(const s16x8*)&xph[go_];             \
      xg[q_][1] = *(const s16x8*)&xpl[go_];             \
    }                                                   \
  } while (0)

// ds_write the staged regs into ring slots (itb..itb+3)
#define DSWRITEX(itb)                                        \
  do {                                                       \
    _Pragma("unroll")                                        \
    for (int q_ = 0; q_ < 4; ++q_) {                         \
      int sl_ = ((itb) + q_) & 7;                            \
      *(s16x8*)&s.xstage[sl_][0][wv][lane * 8] = xg[q_][0];  \
      *(s16x8*)&s.xstage[sl_][1][wv][lane * 8] = xg[q_][1];  \
    }                                                        \
  } while (0)

// 48 MFMAs (3-product split) on one it: x from LDS-read regs, W1 from stage
#define MFMA_IT(xh, xl, Wh, Wl)                                                                        \
  do {                                                                                                 \
    _Pragma("unroll")                                                                                  \
    for (int nt_ = 0; nt_ < 4; ++nt_)                                                                  \
      _Pragma("unroll")                                                                                \
      for (int mt_ = 0; mt_ < 4; ++mt_) {                                                              \
        acc1[mt_][nt_] = __builtin_amdgcn_mfma_f32_16x16x32_bf16(xh[mt_], Wh[nt_], acc1[mt_][nt_], 0, 0, 0); \
        acc1[mt_][nt_] = __builtin_amdgcn_mfma_f32_16x16x32_bf16(xh[mt_], Wl[nt_], acc1[mt_][nt_], 0, 0, 0); \
        acc1[mt_][nt_] = __builtin_amdgcn_mfma_f32_16x16x32_bf16(xl[mt_], Wh[nt_], acc1[mt_][nt_], 0, 0, 0); \
      }                                                                                                \
  } while (0)

// one sub-iteration: ds_read x frags for it, MFMA, then reload W1 stage <- it+2
#define SUBIT(itv, Wh, Wl)                                        \
  do {                                                            \
    s16x8 xh_[4], xl_[4];                                         \
    int sl_ = (itv) & 7;                                          \
    _Pragma("unroll")                                             \
    for (int mt_ = 0; mt_ < 4; ++mt_) {                           \
      xh_[mt_] = *(const s16x8*)&s.xstage[sl_][0][mt_][lane * 8]; \
      xl_[mt_] = *(const s16x8*)&s.xstage[sl_][1][mt_][lane * 8]; \
    }                                                             \
    MFMA_IT(xh_, xl_, Wh, Wl);                                    \
    if ((itv) + 2 < 32) LOADW1(Wh, Wl, (itv) + 2);                \
  } while (0)

// ---- pass 1: split-precision err[K][B]. BM=64, grid 1024, expert = bx & 7.
__global__ __launch_bounds__(256, 2) void ae_pass1(
    const unsigned short* __restrict__ xph, const unsigned short* __restrict__ xpl,
    const float* __restrict__ x,
    const unsigned short* __restrict__ w1ph, const unsigned short* __restrict__ w1pl,
    const float* __restrict__ b1,
    const unsigned short* __restrict__ w2ph, const unsigned short* __restrict__ w2pl,
    const float* __restrict__ b2, float* __restrict__ err) {
  __shared__ union {
    struct { unsigned short h[64][256]; unsigned short l[64][256]; } hs;  // 65536 B
    unsigned short xstage[8][2][4][512];                                  // 65536 B ring
    float errp[4][64];
  } s;

  const int tid = threadIdx.x;
  const int wv = tid >> 6;
  const int lane = tid & 63;
  const int lo = lane & 15;
  const int quad = lane >> 4;
  const int k = blockIdx.x & 7;
  const int rtile = blockIdx.x >> 3;
  const int r0 = rtile * 64;

  // ---------- phase A: h = relu(x@W1+b1).
  int wo1[4];
#pragma unroll
  for (int nt = 0; nt < 4; ++nt) wo1[nt] = ((k * 16 + wv * 4 + nt) * 32) * 512 + lane * 8;
  const size_t xgbase = ((size_t)(rtile * 4 + wv) * 32) * 512 + lane * 8;

  f32x4 acc1[4][4];
#pragma unroll
  for (int mt = 0; mt < 4; ++mt)
#pragma unroll
    for (int nt = 0; nt < 4; ++nt) acc1[mt][nt] = (f32x4){0.f, 0.f, 0.f, 0.f};

  s16x8 xg[4][2];                 // staged x frags for next group (32 VGPR)
  s16x8 Ah[4], Al[4], Bh[4], Bl[4];
  GLOADX(0);
  LOADW1(Ah, Al, 0);
  LOADW1(Bh, Bl, 1);
  DSWRITEX(0);
  __syncthreads();   // x its 0-3 staged

  for (int g = 0; g < 8; ++g) {
    const int itb = g * 4;
    if (g < 7) GLOADX(itb + 4);      // issue next group's x loads early
    SUBIT(itb + 0, Ah, Al);
    SUBIT(itb + 1, Bh, Bl);
    SUBIT(itb + 2, Ah, Al);
    SUBIT(itb + 3, Bh, Bl);
    if (g < 7) DSWRITEX(itb + 4);    // write-late into the other ring half
    __syncthreads();                 // next group's x staged; ring half freed
  }

  // epilogue A: +b1, relu, split h -> LDS swizzled (C/D: col=lo, row=quad*4+i)
#pragma unroll
  for (int nt = 0; nt < 4; ++nt) {
    float b1v = b1[(size_t)k * NH + wv * 64 + nt * 16 + lo];
#pragma unroll
    for (int mt = 0; mt < 4; ++mt)
#pragma unroll
      for (int i = 0; i < 4; ++i) {
        float v = acc1[mt][nt][i] + b1v;
        v = v > 0.f ? v : 0.f;
        unsigned short vh, vl;
        split2(v, vh, vl);
        int row = mt * 16 + quad * 4 + i, col = wv * 64 + nt * 16 + lo;
        int sc = col ^ ((row & 7) << 3);
        s.hs.h[row][sc] = vh;
        s.hs.l[row][sc] = vl;
      }
  }
  __syncthreads();

  // ---------- phase B: recon = h@W2+b2. Wave wv owns d2-strip [wv*256, +256).
  // Single dt loop: W2 frags read ONCE; mt 0-1 h in regs, mt 2-3 h from LDS.
  s16x8 hh[2][8], hl[2][8];
#pragma unroll
  for (int m = 0; m < 2; ++m) {
    int row = m * 16 + lo;
    int rbase = row * 256;
    int sw = (row & 7) << 3;
#pragma unroll
    for (int ks = 0; ks < 8; ++ks) {
      int off = rbase + ((ks * 32 + quad * 8) ^ sw);
      hh[m][ks] = *(const s16x8*)(&s.hs.h[0][0] + off);
      hl[m][ks] = *(const s16x8*)(&s.hs.l[0][0] + off);
    }
  }

  float eacc[4][4];
#pragma unroll
  for (int mt = 0; mt < 4; ++mt)
#pragma unroll
    for (int i = 0; i < 4; ++i) eacc[mt][i] = 0.f;

  const int w2base = ((k * 64 + wv * 16) * 8) * 512 + lane * 8;

  for (int dt = 0; dt < 16; ++dt) {
    f32x4 acc2[4];
#pragma unroll
    for (int mt = 0; mt < 4; ++mt) acc2[mt] = (f32x4){0.f, 0.f, 0.f, 0.f};

#pragma unroll
    for (int ks = 0; ks < 8; ++ks) {
      int wo = w2base + dt * 4096 + ks * 512;
      s16x8 bh = *(const s16x8*)&w2ph[wo];
      s16x8 bl = *(const s16x8*)&w2pl[wo];
      s16x8 h2h[2], h2l[2];
#pragma unroll
      for (int m = 0; m < 2; ++m) {
        int row = (2 + m) * 16 + lo;
        int off = row * 256 + ((ks * 32 + quad * 8) ^ ((row & 7) << 3));
        h2h[m] = *(const s16x8*)(&s.hs.h[0][0] + off);
        h2l[m] = *(const s16x8*)(&s.hs.l[0][0] + off);
      }
#pragma unroll
      for (int m = 0; m < 2; ++m) {
        acc2[m] = __builtin_amdgcn_mfma_f32_16x16x32_bf16(hh[m][ks], bh, acc2[m], 0, 0, 0);
        acc2[m] = __builtin_amdgcn_mfma_f32_16x16x32_bf16(hh[m][ks], bl, acc2[m], 0, 0, 0);
        acc2[m] = __builtin_amdgcn_mfma_f32_16x16x32_bf16(hl[m][ks], bh, acc2[m], 0, 0, 0);
        acc2[2 + m] = __builtin_amdgcn_mfma_f32_16x16x32_bf16(h2h[m], bh, acc2[2 + m], 0, 0, 0);
        acc2[2 + m] = __builtin_amdgcn_mfma_f32_16x16x32_bf16(h2h[m], bl, acc2[2 + m], 0, 0, 0);
        acc2[2 + m] = __builtin_amdgcn_mfma_f32_16x16x32_bf16(h2l[m], bh, acc2[2 + m], 0, 0, 0);
      }
    }
    const int d2 = wv * 256 + dt * 16 + lo;
    float b2v = b2[(size_t)k * ND + d2];
#pragma unroll
    for (int mt = 0; mt < 4; ++mt)
#pragma unroll
      for (int i = 0; i < 4; ++i) {
        int row = mt * 16 + quad * 4 + i;
        float rec = acc2[mt][i] + b2v;
        float xv = x[(size_t)(r0 + row) * ND + d2];
        float dd = rec - xv;
        eacc[mt][i] += dd * dd;
      }
  }

  __syncthreads();   // all hs reads done before errp aliases the union
#pragma unroll
  for (int mt = 0; mt < 4; ++mt)
#pragma unroll
    for (int i = 0; i < 4; ++i) {
      float v = eacc[mt][i];
      v += __shfl_xor(v, 1, 16);
      v += __shfl_xor(v, 2, 16);
      v += __shfl_xor(v, 4, 16);
      v += __shfl_xor(v, 8, 16);
      if (lo == 0) s.errp[wv][mt * 16 + quad * 4 + i] = v;
    }
  __syncthreads();
  if (tid < 64)
    err[(size_t)k * NB + r0 + tid] =
        (s.errp[0][tid] + s.errp[1][tid] + s.errp[2][tid] + s.errp[3][tid]) * (1.0f / (float)ND);
}

// ---- argmin + bucket rows per expert
__global__ __launch_bounds__(256) void ae_argmin(const float* __restrict__ err,
                                                 unsigned int* __restrict__ cnt,
                                                 int* __restrict__ bucket) {
  __shared__ unsigned int lc[KE];
  __shared__ unsigned int base[KE];
  int tid = threadIdx.x;
  if (tid < KE) lc[tid] = 0;
  __syncthreads();
  int b = blockIdx.x * 256 + tid;
  float best = err[b];
  int kmin = 0;
#pragma unroll
  for (int j = 1; j < KE; ++j) {
    float e = err[(size_t)j * NB + b];
    if (e < best) { best = e; kmin = j; }   // strict < == first-min (jnp.argmin)
  }
  unsigned int lpos = atomicAdd(&lc[kmin], 1u);
  __syncthreads();
  if (tid < KE) base[tid] = atomicAdd(&cnt[tid], lc[tid]);
  __syncthreads();
  bucket[(size_t)kmin * NB + (int)(base[kmin] + lpos)] = b;
}

// ---- pass 2: recompute winner rows (bf16-hi, packed W frags), write f32 out
__global__ __launch_bounds__(256) void ae_pass2(
    const float* __restrict__ x,
    const unsigned short* __restrict__ w1ph, const float* __restrict__ b1,
    const unsigned short* __restrict__ w2ph, const float* __restrict__ b2,
    const unsigned int* __restrict__ cnt, const int* __restrict__ bucket,
    float* __restrict__ out) {
  __shared__ unsigned short hs[64][NH + 8];   // 33792 B
  __shared__ unsigned short xs[64][136];      // 17408 B (4 its x 32 cols + 8 pad)
  __shared__ int rid[64];

  const int k = blockIdx.x & 7;
  const int cv = (int)cnt[k];
  const int t0 = (blockIdx.x >> 3) * 64;
  if (t0 >= cv) return;                     // uniform exit before any barrier
  const int nrows = min(64, cv - t0);

  const int tid = threadIdx.x;
  const int wv = tid >> 6;
  const int lane = tid & 63;
  const int lo = lane & 15;
  const int quad = lane >> 4;
  const int srow = tid >> 2, scol = (tid & 3) * 8;

  if (tid < 64) {
    int idx = t0 + tid;
    rid[tid] = bucket[(size_t)k * NB + (idx < cv ? idx : t0)];
  }
  __syncthreads();
  const int grow = rid[srow];

  f32x4 acc1[4][4];
#pragma unroll
  for (int mt = 0; mt < 4; ++mt)
#pragma unroll
    for (int nt = 0; nt < 4; ++nt) acc1[mt][nt] = (f32x4){0.f, 0.f, 0.f, 0.f};

  for (int c = 0; c < 8; ++c) {
    // stage 4 its of x rows (128 cols) for this chunk
    float4 xa[4], xb[4];
#pragma unroll
    for (int j = 0; j < 4; ++j) {
      xa[j] = *(const float4*)&x[(size_t)grow * ND + c * 128 + j * 32 + scol];
      xb[j] = *(const float4*)&x[(size_t)grow * ND + c * 128 + j * 32 + scol + 4];
    }
    __syncthreads();   // prev chunk's frag reads done
#pragma unroll
    for (int j = 0; j < 4; ++j) {
      unsigned short t[8];
      t[0] = f2bf(xa[j].x); t[1] = f2bf(xa[j].y); t[2] = f2bf(xa[j].z); t[3] = f2bf(xa[j].w);
      t[4] = f2bf(xb[j].x); t[5] = f2bf(xb[j].y); t[6] = f2bf(xb[j].z); t[7] = f2bf(xb[j].w);
      *(u16x8*)&xs[srow][j * 32 + scol] = *(u16x8*)t;
    }
    __syncthreads();
#pragma unroll
    for (int j = 0; j < 4; ++j) {
      const int it = c * 4 + j;
      s16x8 bfr[4];
#pragma unroll
      for (int nt = 0; nt < 4; ++nt)
        bfr[nt] = *(const s16x8*)&w1ph[(((size_t)(k * 16 + wv * 4 + nt) * 32) + it) * 512 + lane * 8];
      s16x8 af[4];
#pragma unroll
      for (int mt = 0; mt < 4; ++mt) af[mt] = *(const s16x8*)&xs[mt * 16 + lo][j * 32 + quad * 8];
#pragma unroll
      for (int mt = 0; mt < 4; ++mt)
#pragma unroll
        for (int nt = 0; nt < 4; ++nt)
          acc1[mt][nt] = __builtin_amdgcn_mfma_f32_16x16x32_bf16(af[mt], bfr[nt], acc1[mt][nt], 0, 0, 0);
    }
  }
  __syncthreads();

#pragma unroll
  for (int nt = 0; nt < 4; ++nt) {
    float b1v = b1[(size_t)k * NH + wv * 64 + nt * 16 + lo];
#pragma unroll
    for (int mt = 0; mt < 4; ++mt)
#pragma unroll
      for (int i = 0; i < 4; ++i) {
        float v = acc1[mt][nt][i] + b1v;
        v = v > 0.f ? v : 0.f;
        hs[mt * 16 + quad * 4 + i][wv * 64 + nt * 16 + lo] = f2bf(v);
      }
  }
  __syncthreads();

  // phase B: wave wv owns rows [wv*16, +16); d2 chunks of 32; no barriers.
  for (int c = 0; c < 32; ++c) {
    f32x4 acc2[2];
    acc2[0] = (f32x4){0.f, 0.f, 0.f, 0.f};
    acc2[1] = (f32x4){0.f, 0.f, 0.f, 0.f};
#pragma unroll
    for (int ks = 0; ks < 8; ++ks) {
      s16x8 af = *(const s16x8*)&hs[wv * 16 + lo][ks * 32 + quad * 8];
#pragma unroll
      for (int nt = 0; nt < 2; ++nt) {
        s16x8 bfr = *(const s16x8*)&w2ph[(((size_t)(k * 64 + c * 2 + nt) * 8) + ks) * 512 + lane * 8];
        acc2[nt] = __builtin_amdgcn_mfma_f32_16x16x32_bf16(af, bfr, acc2[nt], 0, 0, 0);
      }
    }
#pragma unroll
    for (int nt = 0; nt < 2; ++nt) {
      float b2v = b2[(size_t)k * ND + c * 32 + nt * 16 + lo];
#pragma unroll
      for (int i = 0; i < 4; ++i) {
        int row = wv * 16 + quad * 4 + i;
        if (row < nrows)
          out[(size_t)rid[row] * ND + c * 32 + nt * 16 + lo] = acc2[nt][i] + b2v;
      }
    }
  }
}

extern "C" void kernel_launch(void* const* d_in, const int* in_sizes, int n_in,
                              void* d_out, int out_size, void* d_ws, size_t ws_size,
                              hipStream_t stream) {
  (void)in_sizes; (void)n_in; (void)out_size; (void)ws_size;
  const float* x  = (const float*)d_in[0];
  const float* W1 = (const float*)d_in[1];
  const float* b1 = (const float*)d_in[2];
  const float* W2 = (const float*)d_in[3];
  const float* b2 = (const float*)d_in[4];
  float* out = (float*)d_out;

  char* ws = (char*)d_ws;
  const size_t szW = (size_t)KE * ND * NH * sizeof(unsigned short);  // 4 MB
  const size_t szX = (size_t)NB * ND * sizeof(unsigned short);       // 16.78 MB
  unsigned short* w1ph = (unsigned short*)(ws);
  unsigned short* w1pl = (unsigned short*)(ws + szW);
  unsigned short* w2ph = (unsigned short*)(ws + 2 * szW);
  unsigned short* w2pl = (unsigned short*)(ws + 3 * szW);
  unsigned short* xph  = (unsigned short*)(ws + 4 * szW);
  unsigned short* xpl  = (unsigned short*)(ws + 4 * szW + szX);
  char* tail           = ws + 4 * szW + 2 * szX;
  float* err           = (float*)tail;
  int* bucket          = (int*)(tail + (size_t)KE * NB * sizeof(float));
  unsigned int* cnt    = (unsigned int*)(tail + (size_t)KE * NB * sizeof(float)
                                         + (size_t)KE * NB * sizeof(int));
  // ws use ~50 MB

  pack_all<<<6144, 256, 0, stream>>>(W1, w1ph, w1pl, W2, w2ph, w2pl, x, xph, xpl, cnt);
  ae_pass1<<<1024, 256, 0, stream>>>(xph, xpl, x, w1ph, w1pl, b1, w2ph, w2pl, b2, err);
  ae_argmin<<<NB / 256, 256, 0, stream>>>(err, cnt, bucket);
  ae_pass2<<<1024, 256, 0, stream>>>(x, w1ph, b1, w2ph, b2, cnt, bucket, out);
}

// Round 4
// 610.960 us; speedup vs baseline: 1.0366x; 1.0366x over previous
//
#include <hip/hip_runtime.h>

// f32 I/O. K=8 expert AEs, B=8192, D=1024, H=256.
//   h = relu(x @ W1[k] + b1[k]); recon = h @ W2[k] + b2[k]
//   err[k,b] = mean((recon-x)^2); out[b] = recon[argmin_k err, b]
// Precision (validated R2): pass1 err via split-bf16 hi/lo 3-product GEMMs;
// pass2 winner recon plain bf16-hi.
// History: R6 (2-stage reg dbuf phase A, reg-held h + W2x2 phase B) = 428us,
// pass1 230us MfmaUtil 40%. R7/R8 staging experiments REGRESSED:
// R8 spilled (WRITE_SIZE 94MB = scratch) + phase-B per-ks h reads through the
// (row&7)<<3 swizzle hit 8-way bank conflicts (37.7M cycles).
// R9 (this rev) = exact R6 base plus two understood deltas:
//  - phase B W2-read-ONCE: h rows 0-31 in regs (as R6); h rows 32-63 stored
//    in MFMA-A-frag-contiguous LDS (bf[m2*2+p][ks][lane*8+j]) so per-ks reads
//    are lane*16B contiguous = conflict-free. Single dt loop, 12 MFMA per
//    W2 hi/lo frag pair. No long-lived staged regs -> no spill.
//  - pack rewrite: W1/W2 fragment packing via coalesced float4 reads +
//    LDS[32][260] transpose (was: 4B loads at 1KB stride).

#define KE 8
#define NB 8192
#define ND 1024
#define NH 256

typedef float f32x4 __attribute__((ext_vector_type(4)));
typedef short s16x8 __attribute__((ext_vector_type(8)));
typedef unsigned short u16x8 __attribute__((ext_vector_type(8)));

__device__ __forceinline__ float bf2f(unsigned short h) {
  union { unsigned int u; float f; } v; v.u = ((unsigned int)h) << 16; return v.f;
}
__device__ __forceinline__ unsigned short f2bf(float f) {
  union { unsigned int u; float f; } v; v.f = f;
  unsigned int u = v.u;
  u += 0x7fffu + ((u >> 16) & 1u);   // RTNE
  return (unsigned short)(u >> 16);
}
__device__ __forceinline__ void split2(float x, unsigned short& hi, unsigned short& lo) {
  hi = f2bf(x);
  lo = f2bf(x - bf2f(hi));
}

// ---- fused pack: W1, W2 (LDS-transpose path), x (direct path); zeroes cnt.
// blocks [0,256):    W1 tile (k=bx>>5, ks=bx&31): rows ks*32..+32 of [1024][256]
// blocks [256,512):  W2 tile (k, ks=0..7, q=0..3): rows ks*32..+32, cols q*256..+256 of [256][1024]
// blocks [512,4608): x  frag g=rt*32+ks (direct, coalesced already)
__global__ __launch_bounds__(256) void pack_all(
    const float* __restrict__ W1, unsigned short* __restrict__ w1oh, unsigned short* __restrict__ w1ol,
    const float* __restrict__ W2, unsigned short* __restrict__ w2oh, unsigned short* __restrict__ w2ol,
    const float* __restrict__ xin, unsigned short* __restrict__ xoh, unsigned short* __restrict__ xol,
    unsigned int* __restrict__ cnt) {
  __shared__ float t[32][260];   // 33.3 KB; rows 1040 B (16B-aligned), +4 pad
  const int bx = blockIdx.x;
  const int tid = threadIdx.x;
  if (bx == 0 && tid < KE) cnt[tid] = 0;

  if (bx < 512) {
    // ---- W matrices via LDS transpose
    const bool isW1 = bx < 256;
    const int b = isW1 ? bx : bx - 256;
    int k, ks, q, CLEN, rowbase, c0;
    const float* src;
    unsigned short *oh, *ol;
    if (isW1) {
      k = b >> 5; ks = b & 31; q = 0;
      CLEN = 256; rowbase = k * ND + ks * 32; c0 = 0;
      src = W1; oh = w1oh; ol = w1ol;
    } else {
      k = b >> 5; ks = (b >> 2) & 7; q = b & 3;
      CLEN = 1024; rowbase = k * NH + ks * 32; c0 = q * 256;
      src = W2; oh = w2oh; ol = w2ol;
    }
    // stage 32 rows x 256 cols, coalesced float4
#pragma unroll
    for (int tl = 0; tl < 8; ++tl) {
      int idx = tl * 256 + tid;          // 2048 float4 slots, 64 per row
      int r = idx >> 6;
      int c4 = (idx & 63) * 4;
      float4 v = *(const float4*)&src[(size_t)(rowbase + r) * CLEN + c0 + c4];
      *(float4*)&t[r][c4] = v;           // contiguous b128 -> conflict-free
    }
    __syncthreads();
    // emit 16 ct-tiles x 64 lanes = 1024 slots, 4 per thread
#pragma unroll
    for (int tl = 0; tl < 4; ++tl) {
      int slot = tl * 256 + tid;
      int ct = slot >> 6, l = slot & 63;
      unsigned short th[8], tlw[8];
#pragma unroll
      for (int j = 0; j < 8; ++j)
        split2(t[(l >> 4) * 8 + j][ct * 16 + (l & 15)], th[j], tlw[j]);
      size_t g = isW1 ? ((size_t)(k * 16 + ct) * 32 + ks)
                      : ((size_t)(k * 64 + q * 16 + ct) * 8 + ks);
      size_t o = (g * 64 + l) * 8;
      *(u16x8*)&oh[o] = *(u16x8*)th;
      *(u16x8*)&ol[o] = *(u16x8*)tlw;
    }
  } else {                                   // ---- pack x (direct)
    int gid = (bx - 512) * 256 + tid;        // 1048576
    int L = gid & 63;
    int g = gid >> 6;
    int ks = g & 31;
    int rt = g >> 5;
    int row = rt * 16 + (L & 15);
    int kd0 = ks * 32 + (L >> 4) * 8;
    float4 a = *(const float4*)&xin[(size_t)row * ND + kd0];
    float4 b4 = *(const float4*)&xin[(size_t)row * ND + kd0 + 4];
    unsigned short th[8], tlw[8];
    split2(a.x, th[0], tlw[0]); split2(a.y, th[1], tlw[1]);
    split2(a.z, th[2], tlw[2]); split2(a.w, th[3], tlw[3]);
    split2(b4.x, th[4], tlw[4]); split2(b4.y, th[5], tlw[5]);
    split2(b4.z, th[6], tlw[6]); split2(b4.w, th[7], tlw[7]);
    size_t o = ((size_t)g * 64 + L) * 8;
    *(u16x8*)&xoh[o] = *(u16x8*)th;
    *(u16x8*)&xol[o] = *(u16x8*)tlw;
  }
}

// load one phase-A stage (16 frags, 256B/lane) into named register buffers
#define LOAD_STAGE(ah, al, bh, bl, it)                  \
  do {                                                  \
    _Pragma("unroll")                                   \
    for (int q_ = 0; q_ < 4; ++q_) {                    \
      int o_ = xo[q_] + (it) * 512;                     \
      ah[q_] = *(const s16x8*)&xph[o_];                 \
      al[q_] = *(const s16x8*)&xpl[o_];                 \
    }                                                   \
    _Pragma("unroll")                                   \
    for (int q_ = 0; q_ < 4; ++q_) {                    \
      int o_ = wo1[q_] + (it) * 512;                    \
      bh[q_] = *(const s16x8*)&w1ph[o_];                \
      bl[q_] = *(const s16x8*)&w1pl[o_];                \
    }                                                   \
  } while (0)

// 48 MFMAs (3-product split) on one stage
#define MFMA_STAGE(ah, al, bh, bl)                                                                   \
  do {                                                                                               \
    _Pragma("unroll")                                                                                \
    for (int nt_ = 0; nt_ < 4; ++nt_)                                                                \
      _Pragma("unroll")                                                                              \
      for (int mt_ = 0; mt_ < 4; ++mt_) {                                                            \
        acc1[mt_][nt_] = __builtin_amdgcn_mfma_f32_16x16x32_bf16(ah[mt_], bh[nt_], acc1[mt_][nt_], 0, 0, 0); \
        acc1[mt_][nt_] = __builtin_amdgcn_mfma_f32_16x16x32_bf16(ah[mt_], bl[nt_], acc1[mt_][nt_], 0, 0, 0); \
        acc1[mt_][nt_] = __builtin_amdgcn_mfma_f32_16x16x32_bf16(al[mt_], bh[nt_], acc1[mt_][nt_], 0, 0, 0); \
      }                                                                                              \
  } while (0)

// ---- pass 1: split-precision err[K][B]. BM=64, grid 1024, expert = bx & 7.
__global__ __launch_bounds__(256, 2) void ae_pass1(
    const unsigned short* __restrict__ xph, const unsigned short* __restrict__ xpl,
    const float* __restrict__ x,
    const unsigned short* __restrict__ w1ph, const unsigned short* __restrict__ w1pl,
    const float* __restrict__ b1,
    const unsigned short* __restrict__ w2ph, const unsigned short* __restrict__ w2pl,
    const float* __restrict__ b2, float* __restrict__ err) {
  __shared__ union {
    struct {
      unsigned short h[32][256];     // h rows 0-31, hi, XOR-swizzled   (16 KB)
      unsigned short l[32][256];     // h rows 0-31, lo                 (16 KB)
      unsigned short bf[4][8][512];  // h rows 32-63 in A-frag layout   (32 KB)
                                     // [m2*2+p][ks][lane*8+j]
    } hs;
    float errp[4][64];
  } s;

  const int tid = threadIdx.x;
  const int wv = tid >> 6;
  const int lane = tid & 63;
  const int lo = lane & 15;
  const int quad = lane >> 4;
  const int k = blockIdx.x & 7;
  const int rtile = blockIdx.x >> 3;
  const int r0 = rtile * 64;

  // ---------- phase A: h = relu(x@W1+b1). Barrier-free, register-pipelined.
  int xo[4], wo1[4];
#pragma unroll
  for (int mt = 0; mt < 4; ++mt) xo[mt] = ((rtile * 4 + mt) * 32) * 512 + lane * 8;
#pragma unroll
  for (int nt = 0; nt < 4; ++nt) wo1[nt] = ((k * 16 + wv * 4 + nt) * 32) * 512 + lane * 8;

  f32x4 acc1[4][4];
#pragma unroll
  for (int mt = 0; mt < 4; ++mt)
#pragma unroll
    for (int nt = 0; nt < 4; ++nt) acc1[mt][nt] = (f32x4){0.f, 0.f, 0.f, 0.f};

  s16x8 Aah[4], Aal[4], Abh[4], Abl[4];
  s16x8 Bah[4], Bal[4], Bbh[4], Bbl[4];
  LOAD_STAGE(Aah, Aal, Abh, Abl, 0);
  LOAD_STAGE(Bah, Bal, Bbh, Bbl, 1);
  for (int it = 0; it < 32; it += 2) {
    MFMA_STAGE(Aah, Aal, Abh, Abl);
    if (it + 2 < 32) LOAD_STAGE(Aah, Aal, Abh, Abl, it + 2);
    MFMA_STAGE(Bah, Bal, Bbh, Bbl);
    if (it + 3 < 32) LOAD_STAGE(Bah, Bal, Bbh, Bbl, it + 3);
  }

  // epilogue A: +b1, relu, split h.
  // rows 0-31 (mt 0,1): swizzled row layout (read once into regs below).
  // rows 32-63 (mt 2,3): A-frag-contiguous layout for conflict-free per-ks reads.
#pragma unroll
  for (int nt = 0; nt < 4; ++nt) {
    float b1v = b1[(size_t)k * NH + wv * 64 + nt * 16 + lo];
    const int ksb = wv * 2 + (nt >> 1);            // frag ks for this (wv,nt)
    const int lbase = 16 * (2 * (nt & 1) + (lo >> 3));
    const int jj = lo & 7;
#pragma unroll
    for (int mt = 0; mt < 4; ++mt)
#pragma unroll
      for (int i = 0; i < 4; ++i) {
        float v = acc1[mt][nt][i] + b1v;
        v = v > 0.f ? v : 0.f;
        unsigned short vh, vl;
        split2(v, vh, vl);
        if (mt < 2) {
          int row = mt * 16 + quad * 4 + i, col = wv * 64 + nt * 16 + lo;
          int sc = col ^ ((row & 7) << 3);
          s.hs.h[row][sc] = vh;
          s.hs.l[row][sc] = vl;
        } else {
          int lp = (quad * 4 + i) + lbase;         // target lane in frag
          int off = lp * 8 + jj;
          s.hs.bf[(mt - 2) * 2 + 0][ksb][off] = vh;
          s.hs.bf[(mt - 2) * 2 + 1][ksb][off] = vl;
        }
      }
  }
  __syncthreads();   // the ONE inter-phase barrier

  // ---------- phase B: recon = h@W2+b2. Wave wv owns d2-strip [wv*256, +256).
  // W2 frags read ONCE. h mt 0-1 in regs (128 VGPR); mt 2-3 from frag-LDS
  // (lane*16B contiguous per ks -> conflict-free).
  s16x8 hh[2][8], hl[2][8];
#pragma unroll
  for (int m = 0; m < 2; ++m) {
    int row = m * 16 + lo;
    int rbase = row * 256;
    int sw = (row & 7) << 3;
#pragma unroll
    for (int ks = 0; ks < 8; ++ks) {
      int off = rbase + ((ks * 32 + quad * 8) ^ sw);
      hh[m][ks] = *(const s16x8*)(&s.hs.h[0][0] + off);
      hl[m][ks] = *(const s16x8*)(&s.hs.l[0][0] + off);
    }
  }

  float eacc[4][4];
#pragma unroll
  for (int mt = 0; mt < 4; ++mt)
#pragma unroll
    for (int i = 0; i < 4; ++i) eacc[mt][i] = 0.f;

  const int w2base = ((k * 64 + wv * 16) * 8) * 512 + lane * 8;

  for (int dt = 0; dt < 16; ++dt) {
    f32x4 acc2[4];
#pragma unroll
    for (int mt = 0; mt < 4; ++mt) acc2[mt] = (f32x4){0.f, 0.f, 0.f, 0.f};

#pragma unroll
    for (int ks = 0; ks < 8; ++ks) {
      int wo = w2base + dt * 4096 + ks * 512;
      s16x8 bh = *(const s16x8*)&w2ph[wo];
      s16x8 bl = *(const s16x8*)&w2pl[wo];
      s16x8 h2h[2], h2l[2];
#pragma unroll
      for (int m = 0; m < 2; ++m) {
        h2h[m] = *(const s16x8*)&s.hs.bf[m * 2 + 0][ks][lane * 8];
        h2l[m] = *(const s16x8*)&s.hs.bf[m * 2 + 1][ks][lane * 8];
      }
#pragma unroll
      for (int m = 0; m < 2; ++m) {
        acc2[m] = __builtin_amdgcn_mfma_f32_16x16x32_bf16(hh[m][ks], bh, acc2[m], 0, 0, 0);
        acc2[m] = __builtin_amdgcn_mfma_f32_16x16x32_bf16(hh[m][ks], bl, acc2[m], 0, 0, 0);
        acc2[m] = __builtin_amdgcn_mfma_f32_16x16x32_bf16(hl[m][ks], bh, acc2[m], 0, 0, 0);
        acc2[2 + m] = __builtin_amdgcn_mfma_f32_16x16x32_bf16(h2h[m], bh, acc2[2 + m], 0, 0, 0);
        acc2[2 + m] = __builtin_amdgcn_mfma_f32_16x16x32_bf16(h2h[m], bl, acc2[2 + m], 0, 0, 0);
        acc2[2 + m] = __builtin_amdgcn_mfma_f32_16x16x32_bf16(h2l[m], bh, acc2[2 + m], 0, 0, 0);
      }
    }
    const int d2 = wv * 256 + dt * 16 + lo;
    float b2v = b2[(size_t)k * ND + d2];
#pragma unroll
    for (int mt = 0; mt < 4; ++mt)
#pragma unroll
      for (int i = 0; i < 4; ++i) {
        int row = mt * 16 + quad * 4 + i;
        float rec = acc2[mt][i] + b2v;
        float xv = x[(size_t)(r0 + row) * ND + d2];
        float dd = rec - xv;
        eacc[mt][i] += dd * dd;
      }
  }

  __syncthreads();   // all hs reads done before errp aliases the union
#pragma unroll
  for (int mt = 0; mt < 4; ++mt)
#pragma unroll
    for (int i = 0; i < 4; ++i) {
      float v = eacc[mt][i];
      v += __shfl_xor(v, 1, 16);
      v += __shfl_xor(v, 2, 16);
      v += __shfl_xor(v, 4, 16);
      v += __shfl_xor(v, 8, 16);
      if (lo == 0) s.errp[wv][mt * 16 + quad * 4 + i] = v;
    }
  __syncthreads();
  if (tid < 64)
    err[(size_t)k * NB + r0 + tid] =
        (s.errp[0][tid] + s.errp[1][tid] + s.errp[2][tid] + s.errp[3][tid]) * (1.0f / (float)ND);
}

// ---- argmin + bucket rows per expert
__global__ __launch_bounds__(256) void ae_argmin(const float* __restrict__ err,
                                                 unsigned int* __restrict__ cnt,
                                                 int* __restrict__ bucket) {
  __shared__ unsigned int lc[KE];
  __shared__ unsigned int base[KE];
  int tid = threadIdx.x;
  if (tid < KE) lc[tid] = 0;
  __syncthreads();
  int b = blockIdx.x * 256 + tid;
  float best = err[b];
  int kmin = 0;
#pragma unroll
  for (int j = 1; j < KE; ++j) {
    float e = err[(size_t)j * NB + b];
    if (e < best) { best = e; kmin = j; }   // strict < == first-min (jnp.argmin)
  }
  unsigned int lpos = atomicAdd(&lc[kmin], 1u);
  __syncthreads();
  if (tid < KE) base[tid] = atomicAdd(&cnt[tid], lc[tid]);
  __syncthreads();
  bucket[(size_t)kmin * NB + (int)(base[kmin] + lpos)] = b;
}

// ---- pass 2: recompute winner rows (bf16-hi, packed W frags), write f32 out
__global__ __launch_bounds__(256) void ae_pass2(
    const float* __restrict__ x,
    const unsigned short* __restrict__ w1ph, const float* __restrict__ b1,
    const unsigned short* __restrict__ w2ph, const float* __restrict__ b2,
    const unsigned int* __restrict__ cnt, const int* __restrict__ bucket,
    float* __restrict__ out) {
  __shared__ unsigned short hs[64][NH + 8];   // 33792 B
  __shared__ unsigned short xs[64][40];       // 5120 B
  __shared__ int rid[64];

  const int k = blockIdx.x & 7;
  const int cv = (int)cnt[k];
  const int t0 = (blockIdx.x >> 3) * 64;
  if (t0 >= cv) return;                     // uniform exit before any barrier
  const int nrows = min(64, cv - t0);

  const int tid = threadIdx.x;
  const int wv = tid >> 6;
  const int lane = tid & 63;
  const int lo = lane & 15;
  const int quad = lane >> 4;
  const int srow = tid >> 2, scol = (tid & 3) * 8;

  if (tid < 64) {
    int idx = t0 + tid;
    rid[tid] = bucket[(size_t)k * NB + (idx < cv ? idx : t0)];
  }
  __syncthreads();
  const int grow = rid[srow];

  f32x4 acc1[4][4];
#pragma unroll
  for (int mt = 0; mt < 4; ++mt)
#pragma unroll
    for (int nt = 0; nt < 4; ++nt) acc1[mt][nt] = (f32x4){0.f, 0.f, 0.f, 0.f};

  for (int it = 0; it < 32; ++it) {
    float4 xa = *(const float4*)&x[(size_t)grow * ND + it * 32 + scol];
    float4 xb = *(const float4*)&x[(size_t)grow * ND + it * 32 + scol + 4];
    s16x8 bfr[4];
#pragma unroll
    for (int nt = 0; nt < 4; ++nt)
      bfr[nt] = *(const s16x8*)&w1ph[(((size_t)(k * 16 + wv * 4 + nt) * 32) + it) * 512 + lane * 8];
    __syncthreads();   // prev frag reads done
    unsigned short t[8];
    t[0] = f2bf(xa.x); t[1] = f2bf(xa.y); t[2] = f2bf(xa.z); t[3] = f2bf(xa.w);
    t[4] = f2bf(xb.x); t[5] = f2bf(xb.y); t[6] = f2bf(xb.z); t[7] = f2bf(xb.w);
    *(u16x8*)&xs[srow][scol] = *(u16x8*)t;
    __syncthreads();
    s16x8 af[4];
#pragma unroll
    for (int mt = 0; mt < 4; ++mt) af[mt] = *(const s16x8*)&xs[mt * 16 + lo][quad * 8];
#pragma unroll
    for (int mt = 0; mt < 4; ++mt)
#pragma unroll
      for (int nt = 0; nt < 4; ++nt)
        acc1[mt][nt] = __builtin_amdgcn_mfma_f32_16x16x32_bf16(af[mt], bfr[nt], acc1[mt][nt], 0, 0, 0);
  }
  __syncthreads();

#pragma unroll
  for (int nt = 0; nt < 4; ++nt) {
    float b1v = b1[(size_t)k * NH + wv * 64 + nt * 16 + lo];
#pragma unroll
    for (int mt = 0; mt < 4; ++mt)
#pragma unroll
      for (int i = 0; i < 4; ++i) {
        float v = acc1[mt][nt][i] + b1v;
        v = v > 0.f ? v : 0.f;
        hs[mt * 16 + quad * 4 + i][wv * 64 + nt * 16 + lo] = f2bf(v);
      }
  }
  __syncthreads();

  // phase B: wave wv owns rows [wv*16, +16); d2 chunks of 32; no barriers.
  for (int c = 0; c < 32; ++c) {
    f32x4 acc2[2];
    acc2[0] = (f32x4){0.f, 0.f, 0.f, 0.f};
    acc2[1] = (f32x4){0.f, 0.f, 0.f, 0.f};
#pragma unroll
    for (int ks = 0; ks < 8; ++ks) {
      s16x8 af = *(const s16x8*)&hs[wv * 16 + lo][ks * 32 + quad * 8];
#pragma unroll
      for (int nt = 0; nt < 2; ++nt) {
        s16x8 bfr = *(const s16x8*)&w2ph[(((size_t)(k * 64 + c * 2 + nt) * 8) + ks) * 512 + lane * 8];
        acc2[nt] = __builtin_amdgcn_mfma_f32_16x16x32_bf16(af, bfr, acc2[nt], 0, 0, 0);
      }
    }
#pragma unroll
    for (int nt = 0; nt < 2; ++nt) {
      float b2v = b2[(size_t)k * ND + c * 32 + nt * 16 + lo];
#pragma unroll
      for (int i = 0; i < 4; ++i) {
        int row = wv * 16 + quad * 4 + i;
        if (row < nrows)
          out[(size_t)rid[row] * ND + c * 32 + nt * 16 + lo] = acc2[nt][i] + b2v;
      }
    }
  }
}

extern "C" void kernel_launch(void* const* d_in, const int* in_sizes, int n_in,
                              void* d_out, int out_size, void* d_ws, size_t ws_size,
                              hipStream_t stream) {
  (void)in_sizes; (void)n_in; (void)out_size; (void)ws_size;
  const float* x  = (const float*)d_in[0];
  const float* W1 = (const float*)d_in[1];
  const float* b1 = (const float*)d_in[2];
  const float* W2 = (const float*)d_in[3];
  const float* b2 = (const float*)d_in[4];
  float* out = (float*)d_out;

  char* ws = (char*)d_ws;
  const size_t szW = (size_t)KE * ND * NH * sizeof(unsigned short);  // 4 MB
  const size_t szX = (size_t)NB * ND * sizeof(unsigned short);       // 16.78 MB
  unsigned short* w1ph = (unsigned short*)(ws);
  unsigned short* w1pl = (unsigned short*)(ws + szW);
  unsigned short* w2ph = (unsigned short*)(ws + 2 * szW);
  unsigned short* w2pl = (unsigned short*)(ws + 3 * szW);
  unsigned short* xph  = (unsigned short*)(ws + 4 * szW);
  unsigned short* xpl  = (unsigned short*)(ws + 4 * szW + szX);
  char* tail           = ws + 4 * szW + 2 * szX;
  float* err           = (float*)tail;
  int* bucket          = (int*)(tail + (size_t)KE * NB * sizeof(float));
  unsigned int* cnt    = (unsigned int*)(tail + (size_t)KE * NB * sizeof(float)
                                         + (size_t)KE * NB * sizeof(int));
  // ws use ~50 MB

  pack_all<<<4608, 256, 0, stream>>>(W1, w1ph, w1pl, W2, w2ph, w2pl, x, xph, xpl, cnt);
  ae_pass1<<<1024, 256, 0, stream>>>(xph, xpl, x, w1ph, w1pl, b1, w2ph, w2pl, b2, err);
  ae_argmin<<<NB / 256, 256, 0, stream>>>(err, cnt, bucket);
  ae_pass2<<<1024, 256, 0, stream>>>(x, w1ph, b1, w2ph, b2, cnt, bucket, out);
}

// Round 5
// 422.356 us; speedup vs baseline: 1.4996x; 1.4466x over previous
//
#include <hip/hip_runtime.h>

// f32 I/O. K=8 expert AEs, B=8192, D=1024, H=256.
//   h = relu(x @ W1[k] + b1[k]); recon = h @ W2[k] + b2[k]
//   err[k,b] = mean((recon-x)^2); out[b] = recon[argmin_k err, b]
// Precision (validated R2): pass1 err via split-bf16 hi/lo 3-product GEMMs;
// pass2 winner recon plain bf16-hi.
// R6 (verified 427.8us, pass1 230us, MfmaUtil 40%): 2-stage reg double-buffer
// phase A; phase B h-in-regs per mc-pass, W2 streamed twice.
// R8/R9 structural experiments both REGRESSED (spill / per-ks LDS reads on the
// shared LDS pipe + W2 stream falling out of cache). Reverted to exact R6.
// R10 (this rev) = R6 + ONE change: XCD-locality block swizzle in ae_pass1.
//   R6's FETCH 287MB ~= 8x the x-frag bytes: blocks bx=rtile*8+k put the 8
//   expert-blocks of a rtile on 8 DIFFERENT XCDs (XCD = bx%8), so every XCD
//   L2 re-fetches the same x slice. Re-encode bx bits [r_hi|k|r_lo] so
//   XCD = bx%8 = rtile%8: all 8 experts of a rtile share one XCD's L2 ->
//   x ingress ~8x less; W1[k]/W2[k] dedup'd across the 8 co-resident
//   rtile-blocks. Bijective remap, zero correctness risk.

#define KE 8
#define NB 8192
#define ND 1024
#define NH 256

typedef float f32x4 __attribute__((ext_vector_type(4)));
typedef short s16x8 __attribute__((ext_vector_type(8)));
typedef unsigned short u16x8 __attribute__((ext_vector_type(8)));

__device__ __forceinline__ float bf2f(unsigned short h) {
  union { unsigned int u; float f; } v; v.u = ((unsigned int)h) << 16; return v.f;
}
__device__ __forceinline__ unsigned short f2bf(float f) {
  union { unsigned int u; float f; } v; v.f = f;
  unsigned int u = v.u;
  u += 0x7fffu + ((u >> 16) & 1u);   // RTNE
  return (unsigned short)(u >> 16);
}
__device__ __forceinline__ void split2(float x, unsigned short& hi, unsigned short& lo) {
  hi = f2bf(x);
  lo = f2bf(x - bf2f(hi));
}

// ---- fused pack: W1, W2, x -> frag-ordered hi/lo arrays; also zeroes cnt.
__global__ __launch_bounds__(256) void pack_all(
    const float* __restrict__ W1, unsigned short* __restrict__ w1oh, unsigned short* __restrict__ w1ol,
    const float* __restrict__ W2, unsigned short* __restrict__ w2oh, unsigned short* __restrict__ w2ol,
    const float* __restrict__ xin, unsigned short* __restrict__ xoh, unsigned short* __restrict__ xol,
    unsigned int* __restrict__ cnt) {
  const int bx = blockIdx.x;
  const int tid = threadIdx.x;
  if (bx == 0 && tid < KE) cnt[tid] = 0;

  if (bx < 1024) {                           // ---- pack W1
    int gid = bx * 256 + tid;
    int L = gid & 63;
    int g = gid >> 6;
    int ks = g & 31;
    int ct = (g >> 5) & 15;
    int k = g >> 9;
    int col = ct * 16 + (L & 15);
    int kd0 = ks * 32 + (L >> 4) * 8;
    unsigned short th[8], tl[8];
#pragma unroll
    for (int j = 0; j < 8; ++j) {
      float v = W1[((size_t)k * ND + kd0 + j) * NH + col];
      split2(v, th[j], tl[j]);
    }
    size_t o = ((size_t)g * 64 + L) * 8;
    *(u16x8*)&w1oh[o] = *(u16x8*)th;
    *(u16x8*)&w1ol[o] = *(u16x8*)tl;
  } else if (bx < 2048) {                    // ---- pack W2
    int gid = (bx - 1024) * 256 + tid;
    int L = gid & 63;
    int g = gid >> 6;
    int ks = g & 7;
    int dt = (g >> 3) & 63;
    int k = g >> 9;
    int d2 = dt * 16 + (L & 15);
    int h0 = ks * 32 + (L >> 4) * 8;
    unsigned short th[8], tl[8];
#pragma unroll
    for (int j = 0; j < 8; ++j) {
      float v = W2[((size_t)k * NH + h0 + j) * ND + d2];
      split2(v, th[j], tl[j]);
    }
    size_t o = ((size_t)g * 64 + L) * 8;
    *(u16x8*)&w2oh[o] = *(u16x8*)th;
    *(u16x8*)&w2ol[o] = *(u16x8*)tl;
  } else {                                   // ---- pack x
    int gid = (bx - 2048) * 256 + tid;
    int L = gid & 63;
    int g = gid >> 6;
    int ks = g & 31;
    int rt = g >> 5;
    int row = rt * 16 + (L & 15);
    int kd0 = ks * 32 + (L >> 4) * 8;
    float4 a = *(const float4*)&xin[(size_t)row * ND + kd0];
    float4 b = *(const float4*)&xin[(size_t)row * ND + kd0 + 4];
    unsigned short th[8], tl[8];
    split2(a.x, th[0], tl[0]); split2(a.y, th[1], tl[1]);
    split2(a.z, th[2], tl[2]); split2(a.w, th[3], tl[3]);
    split2(b.x, th[4], tl[4]); split2(b.y, th[5], tl[5]);
    split2(b.z, th[6], tl[6]); split2(b.w, th[7], tl[7]);
    size_t o = ((size_t)g * 64 + L) * 8;
    *(u16x8*)&xoh[o] = *(u16x8*)th;
    *(u16x8*)&xol[o] = *(u16x8*)tl;
  }
}

// load one phase-A stage (16 frags, 256B/lane) into named register buffers
#define LOAD_STAGE(ah, al, bh, bl, it)                  \
  do {                                                  \
    _Pragma("unroll")                                   \
    for (int q_ = 0; q_ < 4; ++q_) {                    \
      int o_ = xo[q_] + (it) * 512;                     \
      ah[q_] = *(const s16x8*)&xph[o_];                 \
      al[q_] = *(const s16x8*)&xpl[o_];                 \
    }                                                   \
    _Pragma("unroll")                                   \
    for (int q_ = 0; q_ < 4; ++q_) {                    \
      int o_ = wo1[q_] + (it) * 512;                    \
      bh[q_] = *(const s16x8*)&w1ph[o_];                \
      bl[q_] = *(const s16x8*)&w1pl[o_];                \
    }                                                   \
  } while (0)

// 48 MFMAs (3-product split) on one stage
#define MFMA_STAGE(ah, al, bh, bl)                                                                   \
  do {                                                                                               \
    _Pragma("unroll")                                                                                \
    for (int nt_ = 0; nt_ < 4; ++nt_)                                                                \
      _Pragma("unroll")                                                                              \
      for (int mt_ = 0; mt_ < 4; ++mt_) {                                                            \
        acc1[mt_][nt_] = __builtin_amdgcn_mfma_f32_16x16x32_bf16(ah[mt_], bh[nt_], acc1[mt_][nt_], 0, 0, 0); \
        acc1[mt_][nt_] = __builtin_amdgcn_mfma_f32_16x16x32_bf16(ah[mt_], bl[nt_], acc1[mt_][nt_], 0, 0, 0); \
        acc1[mt_][nt_] = __builtin_amdgcn_mfma_f32_16x16x32_bf16(al[mt_], bh[nt_], acc1[mt_][nt_], 0, 0, 0); \
      }                                                                                              \
  } while (0)

// ---- pass 1: split-precision err[K][B]. BM=64, grid 1024.
// XCD-locality decode: bx bits [r_hi | k(3b) | r_lo(3b)] so that
// XCD (= bx % 8 round-robin) == rtile % 8: all 8 expert-blocks of a rtile
// co-reside on one XCD and share its L2 for the x streams.
__global__ __launch_bounds__(256, 2) void ae_pass1(
    const unsigned short* __restrict__ xph, const unsigned short* __restrict__ xpl,
    const float* __restrict__ x,
    const unsigned short* __restrict__ w1ph, const unsigned short* __restrict__ w1pl,
    const float* __restrict__ b1,
    const unsigned short* __restrict__ w2ph, const unsigned short* __restrict__ w2pl,
    const float* __restrict__ b2, float* __restrict__ err) {
  __shared__ union {
    struct { unsigned short h[64][256]; unsigned short l[64][256]; } hs;  // 65536 B
    float errp[4][64];
  } s;

  const int tid = threadIdx.x;
  const int wv = tid >> 6;
  const int lane = tid & 63;
  const int lo = lane & 15;
  const int quad = lane >> 4;
  const int k = (blockIdx.x >> 3) & 7;
  const int rtile = (int)(((blockIdx.x >> 6) << 3) | (blockIdx.x & 7));
  const int r0 = rtile * 64;

  // ---------- phase A: h = relu(x@W1+b1). Barrier-free, register-pipelined.
  int xo[4], wo1[4];
#pragma unroll
  for (int mt = 0; mt < 4; ++mt) xo[mt] = ((rtile * 4 + mt) * 32) * 512 + lane * 8;
#pragma unroll
  for (int nt = 0; nt < 4; ++nt) wo1[nt] = ((k * 16 + wv * 4 + nt) * 32) * 512 + lane * 8;

  f32x4 acc1[4][4];
#pragma unroll
  for (int mt = 0; mt < 4; ++mt)
#pragma unroll
    for (int nt = 0; nt < 4; ++nt) acc1[mt][nt] = (f32x4){0.f, 0.f, 0.f, 0.f};

  s16x8 Aah[4], Aal[4], Abh[4], Abl[4];
  s16x8 Bah[4], Bal[4], Bbh[4], Bbl[4];
  LOAD_STAGE(Aah, Aal, Abh, Abl, 0);
  LOAD_STAGE(Bah, Bal, Bbh, Bbl, 1);
  for (int it = 0; it < 32; it += 2) {
    MFMA_STAGE(Aah, Aal, Abh, Abl);
    if (it + 2 < 32) LOAD_STAGE(Aah, Aal, Abh, Abl, it + 2);
    MFMA_STAGE(Bah, Bal, Bbh, Bbl);
    if (it + 3 < 32) LOAD_STAGE(Bah, Bal, Bbh, Bbl, it + 3);
  }

  // epilogue A: +b1, relu, split h -> LDS swizzled (C/D: col=lo, row=quad*4+i)
#pragma unroll
  for (int nt = 0; nt < 4; ++nt) {
    float b1v = b1[(size_t)k * NH + wv * 64 + nt * 16 + lo];
#pragma unroll
    for (int mt = 0; mt < 4; ++mt)
#pragma unroll
      for (int i = 0; i < 4; ++i) {
        float v = acc1[mt][nt][i] + b1v;
        v = v > 0.f ? v : 0.f;
        unsigned short vh, vl;
        split2(v, vh, vl);
        int row = mt * 16 + quad * 4 + i, col = wv * 64 + nt * 16 + lo;
        int sc = col ^ ((row & 7) << 3);
        s.hs.h[row][sc] = vh;
        s.hs.l[row][sc] = vl;
      }
  }
  __syncthreads();   // the ONE inter-phase barrier

  // ---------- phase B: recon = h@W2+b2. Wave wv owns d2-strip [wv*256, +256).
  // h A-frags dt-invariant: hold a 2-row-tile chunk in registers (128 VGPR)
  // and stream W2 frags (disjoint per wave, L2-resident).
  float eacc[4][4];
#pragma unroll
  for (int mt = 0; mt < 4; ++mt)
#pragma unroll
    for (int i = 0; i < 4; ++i) eacc[mt][i] = 0.f;

  const int w2base = ((k * 64 + wv * 16) * 8) * 512 + lane * 8;

  for (int mc = 0; mc < 2; ++mc) {
    s16x8 hh[2][8], hl[2][8];
#pragma unroll
    for (int m2 = 0; m2 < 2; ++m2) {
      int row = (mc * 2 + m2) * 16 + lo;
      int rbase = row * 256;
      int sw = (row & 7) << 3;
#pragma unroll
      for (int ks = 0; ks < 8; ++ks) {
        int off = rbase + ((ks * 32 + quad * 8) ^ sw);
        hh[m2][ks] = *(const s16x8*)(&s.hs.h[0][0] + off);
        hl[m2][ks] = *(const s16x8*)(&s.hs.l[0][0] + off);
      }
    }
    for (int dt = 0; dt < 16; ++dt) {
      f32x4 acc2[2];
      acc2[0] = (f32x4){0.f, 0.f, 0.f, 0.f};
      acc2[1] = (f32x4){0.f, 0.f, 0.f, 0.f};
#pragma unroll
      for (int ks = 0; ks < 8; ++ks) {
        int wo = w2base + dt * 4096 + ks * 512;
        s16x8 bh = *(const s16x8*)&w2ph[wo];
        s16x8 bl = *(const s16x8*)&w2pl[wo];
#pragma unroll
        for (int m2 = 0; m2 < 2; ++m2) {
          acc2[m2] = __builtin_amdgcn_mfma_f32_16x16x32_bf16(hh[m2][ks], bh, acc2[m2], 0, 0, 0);
          acc2[m2] = __builtin_amdgcn_mfma_f32_16x16x32_bf16(hh[m2][ks], bl, acc2[m2], 0, 0, 0);
          acc2[m2] = __builtin_amdgcn_mfma_f32_16x16x32_bf16(hl[m2][ks], bh, acc2[m2], 0, 0, 0);
        }
      }
      const int d2 = wv * 256 + dt * 16 + lo;
      float b2v = b2[(size_t)k * ND + d2];
#pragma unroll
      for (int m2 = 0; m2 < 2; ++m2)
#pragma unroll
        for (int i = 0; i < 4; ++i) {
          int row = (mc * 2 + m2) * 16 + quad * 4 + i;
          float rec = acc2[m2][i] + b2v;
          float xv = x[(size_t)(r0 + row) * ND + d2];
          float dd = rec - xv;
          eacc[mc * 2 + m2][i] += dd * dd;
        }
    }
  }

  __syncthreads();   // all hs reads done before errp aliases the union
#pragma unroll
  for (int mt = 0; mt < 4; ++mt)
#pragma unroll
    for (int i = 0; i < 4; ++i) {
      float v = eacc[mt][i];
      v += __shfl_xor(v, 1, 16);
      v += __shfl_xor(v, 2, 16);
      v += __shfl_xor(v, 4, 16);
      v += __shfl_xor(v, 8, 16);
      if (lo == 0) s.errp[wv][mt * 16 + quad * 4 + i] = v;
    }
  __syncthreads();
  if (tid < 64)
    err[(size_t)k * NB + r0 + tid] =
        (s.errp[0][tid] + s.errp[1][tid] + s.errp[2][tid] + s.errp[3][tid]) * (1.0f / (float)ND);
}

// ---- argmin + bucket rows per expert
__global__ __launch_bounds__(256) void ae_argmin(const float* __restrict__ err,
                                                 unsigned int* __restrict__ cnt,
                                                 int* __restrict__ bucket) {
  __shared__ unsigned int lc[KE];
  __shared__ unsigned int base[KE];
  int tid = threadIdx.x;
  if (tid < KE) lc[tid] = 0;
  __syncthreads();
  int b = blockIdx.x * 256 + tid;
  float best = err[b];
  int kmin = 0;
#pragma unroll
  for (int j = 1; j < KE; ++j) {
    float e = err[(size_t)j * NB + b];
    if (e < best) { best = e; kmin = j; }   // strict < == first-min (jnp.argmin)
  }
  unsigned int lpos = atomicAdd(&lc[kmin], 1u);
  __syncthreads();
  if (tid < KE) base[tid] = atomicAdd(&cnt[tid], lc[tid]);
  __syncthreads();
  bucket[(size_t)kmin * NB + (int)(base[kmin] + lpos)] = b;
}

// ---- pass 2: recompute winner rows (bf16-hi, packed W frags), write f32 out
__global__ __launch_bounds__(256) void ae_pass2(
    const float* __restrict__ x,
    const unsigned short* __restrict__ w1ph, const float* __restrict__ b1,
    const unsigned short* __restrict__ w2ph, const float* __restrict__ b2,
    const unsigned int* __restrict__ cnt, const int* __restrict__ bucket,
    float* __restrict__ out) {
  __shared__ unsigned short hs[64][NH + 8];   // 33792 B
  __shared__ unsigned short xs[64][40];       // 5120 B
  __shared__ int rid[64];

  const int k = blockIdx.x & 7;
  const int cv = (int)cnt[k];
  const int t0 = (blockIdx.x >> 3) * 64;
  if (t0 >= cv) return;                     // uniform exit before any barrier
  const int nrows = min(64, cv - t0);

  const int tid = threadIdx.x;
  const int wv = tid >> 6;
  const int lane = tid & 63;
  const int lo = lane & 15;
  const int quad = lane >> 4;
  const int srow = tid >> 2, scol = (tid & 3) * 8;

  if (tid < 64) {
    int idx = t0 + tid;
    rid[tid] = bucket[(size_t)k * NB + (idx < cv ? idx : t0)];
  }
  __syncthreads();
  const int grow = rid[srow];

  f32x4 acc1[4][4];
#pragma unroll
  for (int mt = 0; mt < 4; ++mt)
#pragma unroll
    for (int nt = 0; nt < 4; ++nt) acc1[mt][nt] = (f32x4){0.f, 0.f, 0.f, 0.f};

  for (int it = 0; it < 32; ++it) {
    float4 xa = *(const float4*)&x[(size_t)grow * ND + it * 32 + scol];
    float4 xb = *(const float4*)&x[(size_t)grow * ND + it * 32 + scol + 4];
    s16x8 bfr[4];
#pragma unroll
    for (int nt = 0; nt < 4; ++nt)
      bfr[nt] = *(const s16x8*)&w1ph[(((size_t)(k * 16 + wv * 4 + nt) * 32) + it) * 512 + lane * 8];
    __syncthreads();   // prev frag reads done
    unsigned short t[8];
    t[0] = f2bf(xa.x); t[1] = f2bf(xa.y); t[2] = f2bf(xa.z); t[3] = f2bf(xa.w);
    t[4] = f2bf(xb.x); t[5] = f2bf(xb.y); t[6] = f2bf(xb.z); t[7] = f2bf(xb.w);
    *(u16x8*)&xs[srow][scol] = *(u16x8*)t;
    __syncthreads();
    s16x8 af[4];
#pragma unroll
    for (int mt = 0; mt < 4; ++mt) af[mt] = *(const s16x8*)&xs[mt * 16 + lo][quad * 8];
#pragma unroll
    for (int mt = 0; mt < 4; ++mt)
#pragma unroll
      for (int nt = 0; nt < 4; ++nt)
        acc1[mt][nt] = __builtin_amdgcn_mfma_f32_16x16x32_bf16(af[mt], bfr[nt], acc1[mt][nt], 0, 0, 0);
  }
  __syncthreads();

#pragma unroll
  for (int nt = 0; nt < 4; ++nt) {
    float b1v = b1[(size_t)k * NH + wv * 64 + nt * 16 + lo];
#pragma unroll
    for (int mt = 0; mt < 4; ++mt)
#pragma unroll
      for (int i = 0; i < 4; ++i) {
        float v = acc1[mt][nt][i] + b1v;
        v = v > 0.f ? v : 0.f;
        hs[mt * 16 + quad * 4 + i][wv * 64 + nt * 16 + lo] = f2bf(v);
      }
  }
  __syncthreads();

  // phase B: wave wv owns rows [wv*16, +16); d2 chunks of 32; no barriers.
  for (int c = 0; c < 32; ++c) {
    f32x4 acc2[2];
    acc2[0] = (f32x4){0.f, 0.f, 0.f, 0.f};
    acc2[1] = (f32x4){0.f, 0.f, 0.f, 0.f};
#pragma unroll
    for (int ks = 0; ks < 8; ++ks) {
      s16x8 af = *(const s16x8*)&hs[wv * 16 + lo][ks * 32 + quad * 8];
#pragma unroll
      for (int nt = 0; nt < 2; ++nt) {
        s16x8 bfr = *(const s16x8*)&w2ph[(((size_t)(k * 64 + c * 2 + nt) * 8) + ks) * 512 + lane * 8];
        acc2[nt] = __builtin_amdgcn_mfma_f32_16x16x32_bf16(af, bfr, acc2[nt], 0, 0, 0);
      }
    }
#pragma unroll
    for (int nt = 0; nt < 2; ++nt) {
      float b2v = b2[(size_t)k * ND + c * 32 + nt * 16 + lo];
#pragma unroll
      for (int i = 0; i < 4; ++i) {
        int row = wv * 16 + quad * 4 + i;
        if (row < nrows)
          out[(size_t)rid[row] * ND + c * 32 + nt * 16 + lo] = acc2[nt][i] + b2v;
      }
    }
  }
}

extern "C" void kernel_launch(void* const* d_in, const int* in_sizes, int n_in,
                              void* d_out, int out_size, void* d_ws, size_t ws_size,
                              hipStream_t stream) {
  (void)in_sizes; (void)n_in; (void)out_size; (void)ws_size;
  const float* x  = (const float*)d_in[0];
  const float* W1 = (const float*)d_in[1];
  const float* b1 = (const float*)d_in[2];
  const float* W2 = (const float*)d_in[3];
  const float* b2 = (const float*)d_in[4];
  float* out = (float*)d_out;

  char* ws = (char*)d_ws;
  const size_t szW = (size_t)KE * ND * NH * sizeof(unsigned short);  // 4 MB
  const size_t szX = (size_t)NB * ND * sizeof(unsigned short);       // 16.78 MB
  unsigned short* w1ph = (unsigned short*)(ws);
  unsigned short* w1pl = (unsigned short*)(ws + szW);
  unsigned short* w2ph = (unsigned short*)(ws + 2 * szW);
  unsigned short* w2pl = (unsigned short*)(ws + 3 * szW);
  unsigned short* xph  = (unsigned short*)(ws + 4 * szW);
  unsigned short* xpl  = (unsigned short*)(ws + 4 * szW + szX);
  char* tail           = ws + 4 * szW + 2 * szX;
  float* err           = (float*)tail;
  int* bucket          = (int*)(tail + (size_t)KE * NB * sizeof(float));
  unsigned int* cnt    = (unsigned int*)(tail + (size_t)KE * NB * sizeof(float)
                                         + (size_t)KE * NB * sizeof(int));
  // ws use ~50 MB

  pack_all<<<6144, 256, 0, stream>>>(W1, w1ph, w1pl, W2, w2ph, w2pl, x, xph, xpl, cnt);
  ae_pass1<<<1024, 256, 0, stream>>>(xph, xpl, x, w1ph, w1pl, b1, w2ph, w2pl, b2, err);
  ae_argmin<<<NB / 256, 256, 0, stream>>>(err, cnt, bucket);
  ae_pass2<<<1024, 256, 0, stream>>>(x, w1ph, b1, w2ph, b2, cnt, bucket, out);
}